// Round 4
// baseline (626.519 us; speedup 1.0000x reference)
//
#include <hip/hip_runtime.h>
#include <hip/hip_cooperative_groups.h>

namespace cg = cooperative_groups;

// PointPillarScatter: out[b, c, y, x] = pillar_features[p, c] where
// coords[p] = (b, z=0, y, x); zeros elsewhere. Output [8, 64, 496, 432] fp32.
//
// R3: gather formulation, float4 loads + 4x4 reg transpose, zero-row.
// R4: runtime coords dtype detection (int64 vs int32) + bounds guard.
// R5: load/store phase split (neutral). R6: plain stores (slightly worse,
// reverted to NT). R7 (this round): fuse init+detect+scatter+gather into
// ONE cooperative kernel with grid.sync() between phases — removes 3
// dispatch drains + the 1-block detect dispatch + the flag round-trip.
// 1024 blocks x 256 thr, __launch_bounds__(256,4) -> 4 blocks/CU on 256
// CUs, co-residency guaranteed for grid.sync().

#define PX_NX 432
#define PX_NY 496
#define PX_C 64
#define PX_NYX (PX_NY * PX_NX) // 214272, divisible by 4
#define CSPLIT 4               // channel groups per (b,y,x4) position
#define GRID_BLOCKS 1024
#define BLOCK_THREADS 256

typedef float floatx4 __attribute__((ext_vector_type(4)));
typedef long longx4 __attribute__((ext_vector_type(4))); // 32 B

__global__ __launch_bounds__(BLOCK_THREADS, 4) void pps_fused(
    const float* __restrict__ feat,
    const int* __restrict__ c32,     // coords viewed as int32 words
    const longx4* __restrict__ c64,  // coords viewed as int64x4 rows
    int* __restrict__ map,           // ws: B*NYX ints
    float* __restrict__ zrow,        // ws: 64 floats after map
    int* __restrict__ flagp,         // ws: dtype flag after zrow
    float* __restrict__ out,
    int P, int map_n, int total) {
    cg::grid_group grid = cg::this_grid();
    const int gid = blockIdx.x * blockDim.x + threadIdx.x;
    const int gsz = GRID_BLOCKS * BLOCK_THREADS; // 262144

    // ---- phase 1: init map to -1, zero-row, dtype flag -----------------
    int4* map4 = (int4*)map;
    const int n4 = map_n >> 2; // 428544, <= 2 iters
    for (int i = gid; i < n4; i += gsz) map4[i] = make_int4(-1, -1, -1, -1);
    if (gid < 64) zrow[gid] = 0.0f;
    if (gid == 0) {
        // int32 layout: word 4p+3 == x coord (nonzero w.p. 431/432 per row).
        // int64 LE layout: those words are high-words/z == 0 always.
        int nz = 0;
#pragma unroll
        for (int p = 0; p < 16; ++p) nz |= c32[4 * p + 3];
        *flagp = (nz == 0) ? 1 : 0; // 1 = int64 coords
    }
    grid.sync();

    // ---- phase 2: scatter pillar ids into the map ----------------------
    const int flag = *flagp; // wave-uniform, L2 broadcast
    for (int p = gid; p < P; p += gsz) {
        long g;
        if (flag) { // int64 coords (batch, z, y, x)
            longx4 cv = c64[p];
            g = cv.x * PX_NYX + cv.y + cv.z * PX_NX + cv.w;
        } else {    // int32 coords
            int4 cv = ((const int4*)c32)[p];
            g = (long)cv.x * PX_NYX + (long)cv.y + (long)cv.z * PX_NX
                + (long)cv.w;
        }
        if (g >= 0 && g < (long)map_n) map[(int)g] = p; // bounds-guarded
    }
    grid.sync();

    // ---- phase 3: gather + write full output ---------------------------
    // One unit = 4 consecutive x positions for one (b, y), 16 channels.
    // float4 feat loads, 4x4 register transpose, coalesced float4 NT
    // stores (lane-consecutive x). Empty positions read the zeroed row.
    for (int i = gid; i < total; i += gsz) { // ~6.5 units/thread
        const int xq = PX_NX / 4; // 108
        int x4 = i % xq;
        int t = i / xq;
        int y = t % PX_NY;
        int t2 = t / PX_NY;
        int b = t2 % 8;  // B==8 fixed by problem
        int cs = t2 / 8; // channel group 0..CSPLIT-1

        int sbase = b * PX_NYX + y * PX_NX + x4 * 4; // divisible by 4
        int4 pid = ((const int4*)map)[sbase >> 2];

        const float* r0 = (pid.x >= 0) ? feat + (size_t)pid.x * PX_C : zrow;
        const float* r1 = (pid.y >= 0) ? feat + (size_t)pid.y * PX_C : zrow;
        const float* r2 = (pid.z >= 0) ? feat + (size_t)pid.z * PX_C : zrow;
        const float* r3 = (pid.w >= 0) ? feat + (size_t)pid.w * PX_C : zrow;

        const int c_lo = cs * (PX_C / CSPLIT); // 16 channels per unit
        float* ob = out + (size_t)b * ((size_t)PX_C * PX_NYX)
                        + (size_t)y * PX_NX + (size_t)x4 * 4;

#pragma unroll
        for (int cc = 0; cc < 4; ++cc) { // 4 chunks of 4 channels
            int c0 = c_lo + cc * 4;
            floatx4 q0 = *(const floatx4*)(r0 + c0);
            floatx4 q1 = *(const floatx4*)(r1 + c0);
            floatx4 q2 = *(const floatx4*)(r2 + c0);
            floatx4 q3 = *(const floatx4*)(r3 + c0);
#pragma unroll
            for (int k = 0; k < 4; ++k) {
                floatx4 v;
                v.x = q0[k];
                v.y = q1[k];
                v.z = q2[k];
                v.w = q3[k];
                __builtin_nontemporal_store(
                    v, (floatx4*)(ob + (size_t)(c0 + k) * PX_NYX));
            }
        }
    }
}

extern "C" void kernel_launch(void* const* d_in, const int* in_sizes, int n_in,
                              void* d_out, int out_size, void* d_ws, size_t ws_size,
                              hipStream_t stream) {
    const float* feat = (const float*)d_in[0];
    const int* c32 = (const int*)d_in[1];
    const longx4* c64 = (const longx4*)d_in[1];
    float* out = (float*)d_out;
    int* map = (int*)d_ws; // B*NY*NX int32 = 6.86 MB + zero row + flag

    int B = out_size / (PX_C * PX_NYX); // 8 (out_size is element count)
    int P = in_sizes[1] / 4;            // 128000 (words / 4 per row)

    int map_n = B * PX_NYX;                    // 1,714,176
    float* zrow = (float*)(map + map_n);       // 64 zeroed floats
    int* flagp = map + map_n + 64;             // dtype flag

    int total = B * PX_NY * (PX_NX / 4) * CSPLIT; // 1,714,176 units

    void* args[] = {(void*)&feat, (void*)&c32, (void*)&c64, (void*)&map,
                    (void*)&zrow, (void*)&flagp, (void*)&out,
                    (void*)&P, (void*)&map_n, (void*)&total};
    hipLaunchCooperativeKernel((const void*)pps_fused, dim3(GRID_BLOCKS),
                               dim3(BLOCK_THREADS), args, 0, stream);
}

// Round 5
// 466.226 us; speedup vs baseline: 1.3438x; 1.3438x over previous
//
#include <hip/hip_runtime.h>

// PointPillarScatter: out[b, c, y, x] = pillar_features[p, c] where
// coords[p] = (b, z=0, y, x); zeros elsewhere. Output [8, 64, 496, 432] fp32.
//
// Gather formulation: build spatial->pillar index map in d_ws (6.9 MB),
// then one pass writes every output element once (coalesced float4 NT stores).
// R3: float4 feat loads + 4x4 register transpose, zero-row.
// R4: runtime coords dtype detection (int64 vs int32) + bounds guard.
// R5: load/store phase split (neutral). R6: plain stores (worse, reverted).
// R7: cooperative fusion (+165 us — coop launch overhead; reverted).
// R8 (this round): CSPLIT=1 — each thread owns all 64 channels of its 4
// positions, so map and feat are read EXACTLY once from HBM (was 4x map,
// ~2x feat with CSPLIT=4: the 4 sibling threads were ~428K apart in
// dispatch order, far beyond L2 residency). Dtype detect folded into the
// scatter as a wave-local ballot (kills the 1-block detect dispatch).

#define PX_NX 432
#define PX_NY 496
#define PX_C 64
#define PX_NYX (PX_NY * PX_NX) // 214272, divisible by 4

typedef float floatx4 __attribute__((ext_vector_type(4)));
typedef long longx4 __attribute__((ext_vector_type(4))); // 32 B

// ---- kernel 1: init index map to -1, zero-row to 0 ----------------------
__global__ void pps_init_map(int4* __restrict__ map4, int n4) {
    int i = blockIdx.x * blockDim.x + threadIdx.x;
    if (i < n4) {
        map4[i] = make_int4(-1, -1, -1, -1);
    }
    // 64-float zero row lives right after the map (n4*4 ints in)
    if (blockIdx.x == 0 && threadIdx.x < 16) {
        map4[n4 + threadIdx.x] = make_int4(0, 0, 0, 0);
    }
}

// ---- kernel 2: scatter pillar ids into the map (wave-local detect) ------
// coords: [P,4] (batch, z, y, x), int32 or int64 — detected per-wave:
// int32 layout: word 4r+3 == x coord of row r (nonzero w.p. 431/432).
// int64 (LE) layout: words 4r+3 land on {z_hi, x_hi, ...} == 0 always.
// All 64 lanes probe rows 0..15 (words are L2-hot, read before any
// early-return so the ballot sees full participation).
__global__ void pps_scatter_ids(const int* __restrict__ c32,
                                const longx4* __restrict__ c64,
                                int* __restrict__ map, int P, int map_n) {
    int lane = threadIdx.x & 63;
    int probe = c32[4 * (lane & 15) + 3];
    bool is64 = (__ballot(probe != 0) == 0ull); // all-zero => int64 coords

    int p = blockIdx.x * blockDim.x + threadIdx.x;
    if (p >= P) return;
    long g;
    if (is64) { // int64 coords (wave-uniform branch)
        longx4 cv = c64[p];
        g = cv.x * PX_NYX + cv.y + cv.z * PX_NX + cv.w;
    } else {    // int32 coords
        int4 cv = ((const int4*)c32)[p];
        g = (long)cv.x * PX_NYX + (long)cv.y + (long)cv.z * PX_NX + (long)cv.w;
    }
    if (g >= 0 && g < (long)map_n) map[(int)g] = p; // bounds-guarded
}

// ---- kernel 3: gather + write full output -------------------------------
// One thread = 4 consecutive x positions for one (b, y), ALL 64 channels.
// Per chunk of 4 channels: 4 float4 feat loads, 4x4 register transpose,
// 4 coalesced float4 NT stores (consecutive lanes -> consecutive x).
// Empty positions read from a zeroed row (no selects). Each feat row and
// each map entry is read by exactly one thread -> minimal HBM reads.
__global__ void pps_gather(const float* __restrict__ feat,
                           const int* __restrict__ map,
                           const float* __restrict__ zrow,
                           float* __restrict__ out, int total) {
    int i = blockIdx.x * blockDim.x + threadIdx.x;
    if (i >= total) return;

    const int xq = PX_NX / 4; // 108
    int x4 = i % xq;
    int t = i / xq;
    int y = t % PX_NY;
    int b = t / PX_NY; // 0..7, B==8 fixed by problem

    int sbase = b * PX_NYX + y * PX_NX + x4 * 4; // divisible by 4
    int4 pid = ((const int4*)map)[sbase >> 2];

    const float* r0 = (pid.x >= 0) ? feat + (size_t)pid.x * PX_C : zrow;
    const float* r1 = (pid.y >= 0) ? feat + (size_t)pid.y * PX_C : zrow;
    const float* r2 = (pid.z >= 0) ? feat + (size_t)pid.z * PX_C : zrow;
    const float* r3 = (pid.w >= 0) ? feat + (size_t)pid.w * PX_C : zrow;

    float* ob = out + (size_t)b * ((size_t)PX_C * PX_NYX)
                    + (size_t)y * PX_NX + (size_t)x4 * 4;

#pragma unroll
    for (int cc = 0; cc < PX_C / 4; ++cc) { // 16 chunks of 4 channels
        int c0 = cc * 4;
        floatx4 q0 = *(const floatx4*)(r0 + c0);
        floatx4 q1 = *(const floatx4*)(r1 + c0);
        floatx4 q2 = *(const floatx4*)(r2 + c0);
        floatx4 q3 = *(const floatx4*)(r3 + c0);
#pragma unroll
        for (int k = 0; k < 4; ++k) {
            floatx4 v;
            v.x = q0[k];
            v.y = q1[k];
            v.z = q2[k];
            v.w = q3[k];
            __builtin_nontemporal_store(
                v, (floatx4*)(ob + (size_t)(c0 + k) * PX_NYX));
        }
    }
}

extern "C" void kernel_launch(void* const* d_in, const int* in_sizes, int n_in,
                              void* d_out, int out_size, void* d_ws, size_t ws_size,
                              hipStream_t stream) {
    const float* feat = (const float*)d_in[0];
    const int* coords32 = (const int*)d_in[1];
    const longx4* coords64 = (const longx4*)d_in[1];
    float* out = (float*)d_out;
    int* map = (int*)d_ws; // B*NY*NX int32 = 6.86 MB + 256 B zero row

    int B = out_size / (PX_C * PX_NYX); // 8 (out_size is element count)
    int P = in_sizes[1] / 4;            // 128000 (elements / 4 per row)

    int map_n = B * PX_NYX;     // 1,714,176
    int map_n4 = map_n / 4;     // 428,544
    const float* zrow = (const float*)(map + map_n); // 64 zeroed floats

    int total = B * PX_NY * (PX_NX / 4); // 428,544 threads (CSPLIT=1)

    pps_init_map<<<(map_n4 + 255) / 256, 256, 0, stream>>>((int4*)map, map_n4);
    pps_scatter_ids<<<(P + 255) / 256, 256, 0, stream>>>(
        coords32, coords64, map, P, map_n);
    pps_gather<<<(total + 255) / 256, 256, 0, stream>>>(feat, map, zrow, out, total);
}